// Round 1
// baseline (6995.113 us; speedup 1.0000x reference)
//
#include <hip/hip_runtime.h>
#include <cstdint>
#include <cstddef>

// ---------------------------------------------------------------------------
// Parser tree-expansion kernel, fp32 correctness-first implementation.
// B=64, S=32, H=1024, R=256, DEPTH=9. Output [64, 512, 1025].
//
// Layout conventions:
//  - Node rows at level d: m = b*N + n, N=2^d, M = 64*N.
//  - Child of parent row m is rows 2m (left) and 2m+1 (right)  -> parent = row>>1.
//    This makes the jnp.repeat of hc/depth an index-map instead of a copy.
// ---------------------------------------------------------------------------

#define SELU_L 1.0507009873554805f
#define SELU_A 1.6732632423543772f

__device__ __forceinline__ float selu_f(float x) {
    return x > 0.f ? SELU_L * x : (SELU_L * SELU_A) * (__expf(x) - 1.f);
}
__device__ __forceinline__ float sigmoid_f(float x) {
    return 1.f / (1.f + __expf(-x));
}

enum { AM_PLAIN = 0, AM_SELU = 1, AM_CONCAT = 2 };
enum { EP_NONE = 0, EP_SELU = 1, EP_BRANCH = 2, EP_RESID = 3 };

// C[m,n] = epi( sum_k A(m,k) * W[n,k] + bias[n] )
// A modes: plain (lda), selu(A) applied on load, concat: k<1024 -> A (lda), else A2 (ld 256).
// Epilogues:
//   EP_NONE:   C[m*ldc+n] = v
//   EP_SELU:   C[m*ldc+n] = selu(v)
//   EP_BRANCH: c=n>>10, j=n&1023;  C[(2m+c)*1024 + j] = selu(v)   (pre-interleaved children)
//   EP_RESID:  C[m*ldc+n] = P[(m>>1)*1024 + n] - selu(v)
// M, N multiples of 64; K multiple of 16; all row strides multiple of 4 floats.
template <int AMODE, int EPI>
__global__ __launch_bounds__(256) void gemm_k(
    int M, int N, int K,
    const float* __restrict__ A, int lda,
    const float* __restrict__ A2,
    const float* __restrict__ W,
    const float* __restrict__ bias,
    float* __restrict__ C, int ldc,
    const float* __restrict__ P)
{
    __shared__ float As[16][68];
    __shared__ float Ws[16][68];

    const int tid = threadIdx.x;
    const int tx = tid & 15;        // N dir
    const int ty = tid >> 4;        // M dir
    const int bm = blockIdx.y * 64;
    const int bn = blockIdx.x * 64;

    const int lrow = tid >> 2;      // 0..63
    const int lk   = (tid & 3) * 4; // 0,4,8,12

    float acc[4][4] = {};

    for (int k0 = 0; k0 < K; k0 += 16) {
        // --- load A tile (64 rows x 16 k), float4 per thread ---
        const float* ap;
        {
            const int row = bm + lrow;
            if (AMODE == AM_CONCAT) {
                if (k0 < 1024) ap = A + (size_t)row * lda + (k0 + lk);
                else           ap = A2 + (size_t)row * 256 + (k0 - 1024 + lk);
            } else {
                ap = A + (size_t)row * lda + (k0 + lk);
            }
        }
        float4 av = *(const float4*)ap;
        if (AMODE == AM_SELU) {
            av.x = selu_f(av.x); av.y = selu_f(av.y);
            av.z = selu_f(av.z); av.w = selu_f(av.w);
        }
        As[lk + 0][lrow] = av.x;
        As[lk + 1][lrow] = av.y;
        As[lk + 2][lrow] = av.z;
        As[lk + 3][lrow] = av.w;

        // --- load W tile (64 out-cols x 16 k) ---
        const float* wp = W + (size_t)(bn + lrow) * K + (k0 + lk);
        float4 wv = *(const float4*)wp;
        Ws[lk + 0][lrow] = wv.x;
        Ws[lk + 1][lrow] = wv.y;
        Ws[lk + 2][lrow] = wv.z;
        Ws[lk + 3][lrow] = wv.w;

        __syncthreads();

#pragma unroll
        for (int kk = 0; kk < 16; ++kk) {
            float a0 = As[kk][ty * 4 + 0];
            float a1 = As[kk][ty * 4 + 1];
            float a2 = As[kk][ty * 4 + 2];
            float a3 = As[kk][ty * 4 + 3];
            float b0 = Ws[kk][tx * 4 + 0];
            float b1 = Ws[kk][tx * 4 + 1];
            float b2 = Ws[kk][tx * 4 + 2];
            float b3 = Ws[kk][tx * 4 + 3];
            acc[0][0] += a0 * b0; acc[0][1] += a0 * b1; acc[0][2] += a0 * b2; acc[0][3] += a0 * b3;
            acc[1][0] += a1 * b0; acc[1][1] += a1 * b1; acc[1][2] += a1 * b2; acc[1][3] += a1 * b3;
            acc[2][0] += a2 * b0; acc[2][1] += a2 * b1; acc[2][2] += a2 * b2; acc[2][3] += a2 * b3;
            acc[3][0] += a3 * b0; acc[3][1] += a3 * b1; acc[3][2] += a3 * b2; acc[3][3] += a3 * b3;
        }
        __syncthreads();
    }

#pragma unroll
    for (int i = 0; i < 4; ++i) {
        const int row = bm + ty * 4 + i;
#pragma unroll
        for (int j = 0; j < 4; ++j) {
            const int col = bn + tx * 4 + j;
            float v = acc[i][j] + bias[col];
            if (EPI == EP_NONE) {
                C[(size_t)row * ldc + col] = v;
            } else if (EPI == EP_SELU) {
                C[(size_t)row * ldc + col] = selu_f(v);
            } else if (EPI == EP_BRANCH) {
                const int c = col >> 10, jj = col & 1023;
                C[(size_t)(2 * row + c) * 1024 + jj] = selu_f(v);
            } else { // EP_RESID
                C[(size_t)row * ldc + col] =
                    P[(size_t)(row >> 1) * 1024 + col] - selu_f(v);
            }
        }
    }
}

// mean over S=32: xc[b,h] = (1/32) * sum_s T[(b*32+s)*1024 + h]
__global__ void mean_kernel(const float* __restrict__ T, float* __restrict__ xc)
{
    const int idx = blockIdx.x * 256 + threadIdx.x; // 64*1024 total
    const int b = idx >> 10, h = idx & 1023;
    const float* p = T + (size_t)b * 32 * 1024 + h;
    float s = 0.f;
#pragma unroll
    for (int si = 0; si < 32; ++si) s += p[si * 1024];
    xc[idx] = s * (1.f / 32.f);
}

// GRU gate fusion. gi: [M,768] (b_ih folded). For !first: gh [M/2,768] (b_hh folded),
// hold [M/2,256], parent = m>>1. For first: gh = b_hh, hold = 0.
__global__ void gates_kernel(int M,
                             const float* __restrict__ gi,
                             const float* __restrict__ gh,
                             const float* __restrict__ b_hh,
                             const float* __restrict__ hold,
                             float* __restrict__ hnew,
                             int first)
{
    const int idx = blockIdx.x * 256 + threadIdx.x;
    if (idx >= M * 256) return;
    const int m = idx >> 8, j = idx & 255;
    const float* gim = gi + (size_t)m * 768;
    const float ir = gim[j], iz = gim[256 + j], in_ = gim[512 + j];
    float hr, hz, hn, h0;
    if (first) {
        hr = b_hh[j]; hz = b_hh[256 + j]; hn = b_hh[512 + j]; h0 = 0.f;
    } else {
        const float* ghm = gh + (size_t)(m >> 1) * 768;
        hr = ghm[j]; hz = ghm[256 + j]; hn = ghm[512 + j];
        h0 = hold[(size_t)(m >> 1) * 256 + j];
    }
    const float r = sigmoid_f(ir + hr);
    const float z = sigmoid_f(iz + hz);
    const float n = tanhf(in_ + r * hn);
    hnew[idx] = (1.f - z) * n + z * h0;
}

// hb + depth update: one 64-lane wave per row.
// depth_out[row*dstride] = (first ? 0 : depth_old[row>>1]) + sigmoid(xh . W_hb + b_hb)
__global__ void hb_kernel(int M,
                          const float* __restrict__ xc, int lda,
                          const float* __restrict__ hc,
                          const float* __restrict__ W_hb,
                          const float* __restrict__ b_hb,
                          const float* __restrict__ depth_old,
                          float* __restrict__ depth_out, int dstride,
                          int first)
{
    const int row = blockIdx.x * 4 + (threadIdx.x >> 6);
    const int lane = threadIdx.x & 63;
    if (row >= M) return;
    const float* xr = xc + (size_t)row * lda;
    float s = 0.f;
#pragma unroll 4
    for (int k = lane; k < 1024; k += 64) s += xr[k] * W_hb[k];
    const float* hr = hc + (size_t)row * 256;
#pragma unroll
    for (int k = lane; k < 256; k += 64) s += hr[k] * W_hb[1024 + k];
#pragma unroll
    for (int off = 32; off; off >>= 1) s += __shfl_down(s, off);
    if (lane == 0) {
        const float hb = sigmoid_f(s + b_hb[0]);
        const float d0 = first ? 0.f : depth_old[row >> 1];
        depth_out[(size_t)row * dstride] = d0 + hb;
    }
}

// out[m*1025 + c] = xc[m*1024 + c] for c<1024
__global__ void copyout_kernel(const float* __restrict__ xc, float* __restrict__ out)
{
    const size_t idx = (size_t)blockIdx.x * 256 + threadIdx.x; // 32768*1024
    const size_t m = idx >> 10, c = idx & 1023;
    out[m * 1025 + c] = xc[idx];
}

extern "C" void kernel_launch(void* const* d_in, const int* in_sizes, int n_in,
                              void* d_out, int out_size, void* d_ws, size_t ws_size,
                              hipStream_t stream)
{
    const float* x        = (const float*)d_in[0];   // [64,32,1024]
    const float* W_hidden = (const float*)d_in[1];   // [1024,1024]
    const float* b_hidden = (const float*)d_in[2];   // [1024]
    const float* W_hb     = (const float*)d_in[3];   // [1,1280]
    const float* b_hb     = (const float*)d_in[4];   // [1]
    const float* W_branch = (const float*)d_in[5];   // [2048,1280]
    const float* b_branch = (const float*)d_in[6];   // [2048]
    const float* W_ih     = (const float*)d_in[7];   // [768,1024]
    const float* W_hh     = (const float*)d_in[8];   // [768,256]
    const float* b_ih     = (const float*)d_in[9];   // [768]
    const float* b_hh     = (const float*)d_in[10];  // [768]
    // d_in[11] = tree_depth (9, compile-time constant here)

    char* ws = (char*)d_ws;
    float* XC0 = (float*)ws; ws += (size_t)134217728;            // 32768 x 1024 f32
    float* XC1 = (float*)ws; ws += (size_t)134217728;
    float* HC0 = (float*)ws; ws += (size_t)33554432;             // 32768 x 256 f32
    float* HC1 = (float*)ws; ws += (size_t)33554432;
    float* D0  = (float*)ws; ws += (size_t)131072;               // 32768 f32
    float* D1  = (float*)ws; ws += (size_t)131072;
    float* S1  = (float*)ws; ws += (size_t)134217728;            // gi / LR / root-T
    float* S2  = (float*)ws; ws += (size_t)50331648;             // gh

    float* out = (float*)d_out; // [64*512, 1025]

    // ---- root: T = selu(selu(x) @ W_hidden^T + b_hidden); xc0 = mean_s(T) ----
    gemm_k<AM_SELU, EP_SELU><<<dim3(1024 / 64, 2048 / 64), 256, 0, stream>>>(
        2048, 1024, 1024, x, 1024, nullptr, W_hidden, b_hidden, S1, 1024, nullptr);
    mean_kernel<<<(64 * 1024) / 256, 256, 0, stream>>>(S1, XC0);

    float* xc_cur = XC0; float* xc_next = XC1;
    float* hc_prev = nullptr; float* hc_new = HC0;
    float* d_prev = nullptr;  float* d_next = D0;

    for (int d = 0; d < 9; ++d) {
        const int M = 64 << d; // 64 .. 16384
        // gi = xc @ W_ih^T + b_ih   [M,768]
        gemm_k<AM_PLAIN, EP_NONE><<<dim3(768 / 64, M / 64), 256, 0, stream>>>(
            M, 768, 1024, xc_cur, 1024, nullptr, W_ih, b_ih, S1, 768, nullptr);
        // gh = hc_prev @ W_hh^T + b_hh  [M/2,768] (read twice via row>>1)
        if (d > 0) {
            gemm_k<AM_PLAIN, EP_NONE><<<dim3(768 / 64, (M / 2) / 64), 256, 0, stream>>>(
                M / 2, 768, 256, hc_prev, 256, nullptr, W_hh, b_hh, S2, 768, nullptr);
        }
        gates_kernel<<<M, 256, 0, stream>>>(M, S1, d > 0 ? S2 : nullptr, b_hh,
                                            hc_prev, hc_new, d == 0 ? 1 : 0);
        hb_kernel<<<(M + 3) / 4, 256, 0, stream>>>(M, xc_cur, 1024, hc_new, W_hb, b_hb,
                                                   d_prev, d_next, 1, d == 0 ? 1 : 0);
        // lr = selu([xc,hc] @ W_branch^T + b_branch), stored interleaved [2M,1024]
        gemm_k<AM_CONCAT, EP_BRANCH><<<dim3(2048 / 64, M / 64), 256, 0, stream>>>(
            M, 2048, 1280, xc_cur, 1024, hc_new, W_branch, b_branch, S1, 1024, nullptr);
        // children: xc_next[r] = xc_cur[r>>1] - selu(LR[r] @ W_hidden^T + b_hidden)
        gemm_k<AM_PLAIN, EP_RESID><<<dim3(1024 / 64, (2 * M) / 64), 256, 0, stream>>>(
            2 * M, 1024, 1024, S1, 1024, nullptr, W_hidden, b_hidden, xc_next, 1024, xc_cur);

        float* t = xc_cur; xc_cur = xc_next; xc_next = t;
        hc_prev = hc_new; hc_new = (hc_new == HC0) ? HC1 : HC0;
        d_prev = d_next;  d_next = (d_next == D0) ? D1 : D0;
    }

    // ---- final GRU + leaf hb, M = 32768 ----
    {
        const int M = 32768;
        gemm_k<AM_PLAIN, EP_NONE><<<dim3(768 / 64, M / 64), 256, 0, stream>>>(
            M, 768, 1024, xc_cur, 1024, nullptr, W_ih, b_ih, S1, 768, nullptr);
        gemm_k<AM_PLAIN, EP_NONE><<<dim3(768 / 64, (M / 2) / 64), 256, 0, stream>>>(
            M / 2, 768, 256, hc_prev, 256, nullptr, W_hh, b_hh, S2, 768, nullptr);
        gates_kernel<<<M, 256, 0, stream>>>(M, S1, S2, b_hh, hc_prev, hc_new, 0);
        hb_kernel<<<M / 4, 256, 0, stream>>>(M, xc_cur, 1024, hc_new, W_hb, b_hb,
                                             d_prev, out + 1024, 1025, 0);
        copyout_kernel<<<(M * 1024) / 256, 256, 0, stream>>>(xc_cur, out);
    }
}

// Round 2
// 1844.279 us; speedup vs baseline: 3.7929x; 3.7929x over previous
//
#include <hip/hip_runtime.h>
#include <hip/hip_bf16.h>
#include <cstdint>
#include <cstddef>

// ---------------------------------------------------------------------------
// Parser tree expansion — round 2: bf16 MFMA GEMMs (16x16x32, fp32 accum).
// B=64, S=32, H=1024, R=256, DEPTH=9. Output [64, 512, 1025] fp32.
//
// Node rows at level d: m = b*N + n; child rows of parent m are 2m, 2m+1
// (parent = row>>1), so jnp.repeat becomes an index map.
//
// GEMM: 128x128 tile, 4 waves x (4x4 of 16x16x32 frags), BK=32,
// global_load_lds width=16 staging, chunk-XOR LDS swizzle (2-way banks).
// ---------------------------------------------------------------------------

#define SELU_L 1.0507009873554805f
#define SELU_A 1.6732632423543772f

__device__ __forceinline__ float selu_f(float x) {
    return x > 0.f ? SELU_L * x : (SELU_L * SELU_A) * (__expf(x) - 1.f);
}
__device__ __forceinline__ float sigmoid_f(float x) {
    return 1.f / (1.f + __expf(-x));
}

typedef __attribute__((ext_vector_type(8))) short s16x8;
typedef __attribute__((ext_vector_type(4))) float f32x4;

__device__ __forceinline__ void gld16(const void* g, void* l) {
    __builtin_amdgcn_global_load_lds(
        (const __attribute__((address_space(1))) uint32_t*)g,
        (__attribute__((address_space(3))) uint32_t*)l, 16, 0, 0);
}

enum { AM_PLAIN = 0, AM_CONCAT = 2 };
enum { EP_NONE = 0, EP_SELU32 = 1, EP_BRANCH = 2, EP_RESID = 3 };

// C = epi(A @ W^T + bias). A: [M,K] bf16 (CONCAT: k<1024 from A (ld 1024),
// k>=1024 from A2 (ld 256)). W: [N,K] bf16. M mult of 64 (clamped staging),
// N mult of 128, K mult of 32.
template <int AMODE, int EPI>
__global__ __launch_bounds__(256) void mgemm(
    int M, int N, int K,
    const __hip_bfloat16* __restrict__ A, int lda,
    const __hip_bfloat16* __restrict__ A2,
    const __hip_bfloat16* __restrict__ W,
    const float* __restrict__ bias,
    void* __restrict__ Cv, int ldc,
    const __hip_bfloat16* __restrict__ P,
    float* __restrict__ C32)
{
    __shared__ short As[4096];   // 128 rows x 32 k, chunk-swizzled
    __shared__ short Bs[4096];

    const int tid  = threadIdx.x;
    const int wave = tid >> 6;
    const int lane = tid & 63;
    const int bm = blockIdx.y * 128;
    const int bn = blockIdx.x * 128;

    // ---- staging descriptors: slot s holds row s>>2, phys chunk s&3 ----
    const int s0 = wave * 128 + lane;
    const int s1 = s0 + 64;
    const int r0 = s0 >> 2, j0 = ((s0 & 3) - (r0 >> 1)) & 3;
    const int r1 = s1 >> 2, j1 = ((s1 & 3) - (r1 >> 1)) & 3;
    const int ga0 = min(bm + r0, M - 1);
    const int ga1 = min(bm + r1, M - 1);

    const short* gA0; const short* gA1;        // PLAIN bases
    const short* gA0b = nullptr; const short* gA1b = nullptr; // CONCAT A2 bases
    if (AMODE == AM_CONCAT) {
        gA0  = (const short*)A  + (size_t)ga0 * 1024 + j0 * 8;
        gA1  = (const short*)A  + (size_t)ga1 * 1024 + j1 * 8;
        gA0b = (const short*)A2 + (size_t)ga0 * 256  + j0 * 8;
        gA1b = (const short*)A2 + (size_t)ga1 * 256  + j1 * 8;
    } else {
        gA0 = (const short*)A + (size_t)ga0 * lda + j0 * 8;
        gA1 = (const short*)A + (size_t)ga1 * lda + j1 * 8;
    }
    const short* gB0 = (const short*)W + (size_t)(bn + r0) * K + j0 * 8;
    const short* gB1 = (const short*)W + (size_t)(bn + r1) * K + j1 * 8;

    short* dA0 = &As[wave * 1024];
    short* dA1 = &As[wave * 1024 + 512];
    short* dB0 = &Bs[wave * 1024];
    short* dB1 = &Bs[wave * 1024 + 512];

    // ---- fragment read offsets (k-invariant) ----
    const int wm = (wave >> 1) * 64, wn = (wave & 1) * 64;
    const int l16 = lane & 15, q4 = lane >> 4;
    int aoff[4], boff[4];
#pragma unroll
    for (int i = 0; i < 4; ++i) {
        int ra = wm + i * 16 + l16;
        aoff[i] = ra * 32 + (((q4 + (ra >> 1)) & 3) << 3);
        int rb = wn + i * 16 + l16;
        boff[i] = rb * 32 + (((q4 + (rb >> 1)) & 3) << 3);
    }

    f32x4 acc[4][4] = {};

    for (int k0 = 0; k0 < K; k0 += 32) {
        if (AMODE == AM_CONCAT) {
            const short* a0 = (k0 < 1024) ? gA0 + k0 : gA0b + (k0 - 1024);
            const short* a1 = (k0 < 1024) ? gA1 + k0 : gA1b + (k0 - 1024);
            gld16(a0, dA0);
            gld16(a1, dA1);
        } else {
            gld16(gA0 + k0, dA0);
            gld16(gA1 + k0, dA1);
        }
        gld16(gB0 + k0, dB0);
        gld16(gB1 + k0, dB1);
        __syncthreads();   // compiler emits vmcnt(0) drain before s_barrier

        s16x8 af[4], bf[4];
#pragma unroll
        for (int i = 0; i < 4; ++i) af[i] = *(const s16x8*)&As[aoff[i]];
#pragma unroll
        for (int i = 0; i < 4; ++i) bf[i] = *(const s16x8*)&Bs[boff[i]];
#pragma unroll
        for (int mi = 0; mi < 4; ++mi)
#pragma unroll
            for (int ni = 0; ni < 4; ++ni)
                acc[mi][ni] = __builtin_amdgcn_mfma_f32_16x16x32_bf16(
                    af[mi], bf[ni], acc[mi][ni], 0, 0, 0);
        __syncthreads();
    }

    // ---- epilogue: C/D layout col=lane&15, row=q4*4+reg ----
    const int crow0 = bm + wm + q4 * 4;
    const int ccol0 = bn + wn + l16;
#pragma unroll
    for (int mi = 0; mi < 4; ++mi) {
#pragma unroll
        for (int r = 0; r < 4; ++r) {
            const int row = crow0 + mi * 16 + r;
            if (row >= M) continue;
#pragma unroll
            for (int ni = 0; ni < 4; ++ni) {
                const int col = ccol0 + ni * 16;
                float v = acc[mi][ni][r] + bias[col];
                if (EPI == EP_NONE) {
                    ((float*)Cv)[(size_t)row * ldc + col] = v;
                } else if (EPI == EP_SELU32) {
                    ((float*)Cv)[(size_t)row * ldc + col] = selu_f(v);
                } else if (EPI == EP_BRANCH) {
                    const int c = col >> 10, jj = col & 1023;
                    ((__hip_bfloat16*)Cv)[(size_t)(2 * row + c) * 1024 + jj] =
                        __float2bfloat16(selu_f(v));
                } else { // EP_RESID
                    const float pv = __bfloat162float(P[(size_t)(row >> 1) * 1024 + col]);
                    const float o = pv - selu_f(v);
                    ((__hip_bfloat16*)Cv)[(size_t)row * 1024 + col] = __float2bfloat16(o);
                    if (C32) C32[(size_t)row * 1024 + col] = o;
                }
            }
        }
    }
}

// ---- elementwise helpers ----
__global__ void cvt_bf16_k(const float* __restrict__ in, __hip_bfloat16* __restrict__ out, int n)
{
    int i = blockIdx.x * 256 + threadIdx.x;
    if (i < n) out[i] = __float2bfloat16(in[i]);
}

__global__ void selu_cvt_k(const float* __restrict__ in, __hip_bfloat16* __restrict__ out, int n)
{
    int i = blockIdx.x * 256 + threadIdx.x;
    if (i < n) out[i] = __float2bfloat16(selu_f(in[i]));
}

// xc[b,h] = mean_s T[(b*32+s)*1024+h], bf16 out
__global__ void mean_kernel(const float* __restrict__ T, __hip_bfloat16* __restrict__ xc)
{
    const int idx = blockIdx.x * 256 + threadIdx.x; // 64*1024
    const int b = idx >> 10, h = idx & 1023;
    const float* p = T + (size_t)b * 32 * 1024 + h;
    float s = 0.f;
#pragma unroll
    for (int si = 0; si < 32; ++si) s += p[si * 1024];
    xc[idx] = __float2bfloat16(s * (1.f / 32.f));
}

// GRU gates: gi [M,768] f32 (b_ih folded), gh [M/2,768] f32 (b_hh folded),
// hold [M/2,256] bf16. first: gh=b_hh, hold=0.
__global__ void gates_kernel(int M,
                             const float* __restrict__ gi,
                             const float* __restrict__ gh,
                             const float* __restrict__ b_hh,
                             const __hip_bfloat16* __restrict__ hold,
                             __hip_bfloat16* __restrict__ hnew,
                             int first)
{
    const int idx = blockIdx.x * 256 + threadIdx.x;
    if (idx >= M * 256) return;
    const int m = idx >> 8, j = idx & 255;
    const float* gim = gi + (size_t)m * 768;
    const float ir = gim[j], iz = gim[256 + j], in_ = gim[512 + j];
    float hr, hz, hn, h0;
    if (first) {
        hr = b_hh[j]; hz = b_hh[256 + j]; hn = b_hh[512 + j]; h0 = 0.f;
    } else {
        const float* ghm = gh + (size_t)(m >> 1) * 768;
        hr = ghm[j]; hz = ghm[256 + j]; hn = ghm[512 + j];
        h0 = __bfloat162float(hold[(size_t)(m >> 1) * 256 + j]);
    }
    const float r = sigmoid_f(ir + hr);
    const float z = sigmoid_f(iz + hz);
    const float n = tanhf(in_ + r * hn);
    hnew[idx] = __float2bfloat16((1.f - z) * n + z * h0);
}

// depth update: one wave per row.
__global__ void hb_kernel(int M,
                          const __hip_bfloat16* __restrict__ xc,
                          const __hip_bfloat16* __restrict__ hc,
                          const float* __restrict__ W_hb,
                          const float* __restrict__ b_hb,
                          const float* __restrict__ depth_old,
                          float* __restrict__ depth_out, int dstride,
                          int first)
{
    const int row = blockIdx.x * 4 + (threadIdx.x >> 6);
    const int lane = threadIdx.x & 63;
    if (row >= M) return;
    const __hip_bfloat16* xr = xc + (size_t)row * 1024;
    float s = 0.f;
#pragma unroll 4
    for (int k = lane; k < 1024; k += 64) s += __bfloat162float(xr[k]) * W_hb[k];
    const __hip_bfloat16* hr = hc + (size_t)row * 256;
#pragma unroll
    for (int k = lane; k < 256; k += 64) s += __bfloat162float(hr[k]) * W_hb[1024 + k];
#pragma unroll
    for (int off = 32; off; off >>= 1) s += __shfl_down(s, off);
    if (lane == 0) {
        const float hb = sigmoid_f(s + b_hb[0]);
        const float d0 = first ? 0.f : depth_old[row >> 1];
        depth_out[(size_t)row * dstride] = d0 + hb;
    }
}

// out[m*1025 + c] = xcf[m*1024 + c]
__global__ void copyout_kernel(const float* __restrict__ xcf, float* __restrict__ out)
{
    const size_t idx = (size_t)blockIdx.x * 256 + threadIdx.x; // 32768*1024
    const size_t m = idx >> 10, c = idx & 1023;
    out[m * 1025 + c] = xcf[idx];
}

extern "C" void kernel_launch(void* const* d_in, const int* in_sizes, int n_in,
                              void* d_out, int out_size, void* d_ws, size_t ws_size,
                              hipStream_t stream)
{
    const float* x        = (const float*)d_in[0];   // [64,32,1024]
    const float* W_hidden = (const float*)d_in[1];   // [1024,1024]
    const float* b_hidden = (const float*)d_in[2];
    const float* W_hb     = (const float*)d_in[3];   // [1,1280]
    const float* b_hb     = (const float*)d_in[4];
    const float* W_branch = (const float*)d_in[5];   // [2048,1280]
    const float* b_branch = (const float*)d_in[6];
    const float* W_ih     = (const float*)d_in[7];   // [768,1024]
    const float* W_hh     = (const float*)d_in[8];   // [768,256]
    const float* b_ih     = (const float*)d_in[9];
    const float* b_hh     = (const float*)d_in[10];

    char* ws = (char*)d_ws;
    size_t off = 0;
    auto alloc = [&](size_t bytes) {
        void* p = ws + off;
        off += (bytes + 255) & ~(size_t)255;
        return p;
    };
    __hip_bfloat16* Whb  = (__hip_bfloat16*)alloc(1024 * 1024 * 2);      // W_hidden bf16
    __hip_bfloat16* Wbb  = (__hip_bfloat16*)alloc(2048 * 1280 * 2);      // W_branch bf16
    __hip_bfloat16* Wib  = (__hip_bfloat16*)alloc(768 * 1024 * 2);       // W_ih bf16
    __hip_bfloat16* Whh  = (__hip_bfloat16*)alloc(768 * 256 * 2);        // W_hh bf16
    __hip_bfloat16* Xs   = (__hip_bfloat16*)alloc((size_t)2048 * 1024 * 2); // selu(x) bf16
    float*          GI   = (float*)alloc((size_t)32768 * 768 * 4);       // gi; also root T [2048,1024]
    __hip_bfloat16* U    = (__hip_bfloat16*)alloc((size_t)32768 * 1024 * 2); // LR bf16 / gh f32 (time-shared)
    __hip_bfloat16* XC0  = (__hip_bfloat16*)alloc((size_t)32768 * 1024 * 2);
    __hip_bfloat16* XC1  = (__hip_bfloat16*)alloc((size_t)32768 * 1024 * 2);
    float*          XCF  = (float*)alloc((size_t)32768 * 1024 * 4);      // leaf xc fp32
    __hip_bfloat16* HC0  = (__hip_bfloat16*)alloc((size_t)32768 * 256 * 2);
    __hip_bfloat16* HC1  = (__hip_bfloat16*)alloc((size_t)32768 * 256 * 2);
    float*          D0   = (float*)alloc(32768 * 4);
    float*          D1   = (float*)alloc(32768 * 4);
    float*          GH   = (float*)U;  // gh fp32 [M/2,768], time-shared with LR

    float* out = (float*)d_out; // [32768, 1025]

    // ---- weight + input conversions ----
    cvt_bf16_k<<<(1024 * 1024 + 255) / 256, 256, 0, stream>>>(W_hidden, Whb, 1024 * 1024);
    cvt_bf16_k<<<(2048 * 1280 + 255) / 256, 256, 0, stream>>>(W_branch, Wbb, 2048 * 1280);
    cvt_bf16_k<<<(768 * 1024 + 255) / 256, 256, 0, stream>>>(W_ih, Wib, 768 * 1024);
    cvt_bf16_k<<<(768 * 256 + 255) / 256, 256, 0, stream>>>(W_hh, Whh, 768 * 256);
    selu_cvt_k<<<(2048 * 1024 + 255) / 256, 256, 0, stream>>>(x, Xs, 2048 * 1024);

    // ---- root: T = selu(Xs @ Wh^T + b); xc0 = mean_s(T) ----
    mgemm<AM_PLAIN, EP_SELU32><<<dim3(1024 / 128, 2048 / 128), 256, 0, stream>>>(
        2048, 1024, 1024, Xs, 1024, nullptr, Whb, b_hidden, GI, 1024, nullptr, nullptr);
    mean_kernel<<<(64 * 1024) / 256, 256, 0, stream>>>(GI, XC0);

    __hip_bfloat16* xc_cur = XC0; __hip_bfloat16* xc_next = XC1;
    __hip_bfloat16* hc_prev = nullptr; __hip_bfloat16* hc_new = HC0;
    float* d_prev = nullptr; float* d_next = D0;

    for (int d = 0; d < 9; ++d) {
        const int M = 64 << d; // 64 .. 16384
        mgemm<AM_PLAIN, EP_NONE><<<dim3(768 / 128, (M + 127) / 128), 256, 0, stream>>>(
            M, 768, 1024, xc_cur, 1024, nullptr, Wib, b_ih, GI, 768, nullptr, nullptr);
        if (d > 0) {
            mgemm<AM_PLAIN, EP_NONE><<<dim3(768 / 128, (M / 2 + 127) / 128), 256, 0, stream>>>(
                M / 2, 768, 256, hc_prev, 256, nullptr, Whh, b_hh, GH, 768, nullptr, nullptr);
        }
        gates_kernel<<<M, 256, 0, stream>>>(M, GI, (const float*)GH, b_hh,
                                            hc_prev, hc_new, d == 0 ? 1 : 0);
        hb_kernel<<<(M + 3) / 4, 256, 0, stream>>>(M, xc_cur, hc_new, W_hb, b_hb,
                                                   d_prev, d_next, 1, d == 0 ? 1 : 0);
        // LR = selu([xc,hc] @ Wb^T + b), interleaved children [2M,1024] bf16
        mgemm<AM_CONCAT, EP_BRANCH><<<dim3(2048 / 128, (M + 127) / 128), 256, 0, stream>>>(
            M, 2048, 1280, xc_cur, 1024, hc_new, Wbb, b_branch, U, 1024, nullptr, nullptr);
        // xc_next[r] = xc_cur[r>>1] - selu(LR[r] @ Wh^T + b); fp32 twin at last level
        mgemm<AM_PLAIN, EP_RESID><<<dim3(1024 / 128, (2 * M) / 128), 256, 0, stream>>>(
            2 * M, 1024, 1024, U, 1024, nullptr, Whb, b_hidden, xc_next, 1024,
            xc_cur, d == 8 ? XCF : nullptr);

        __hip_bfloat16* t = xc_cur; xc_cur = xc_next; xc_next = t;
        hc_prev = hc_new; hc_new = (hc_new == HC0) ? HC1 : HC0;
        d_prev = d_next;  d_next = (d_next == D0) ? D1 : D0;
    }

    // ---- final GRU + leaf depth, M = 32768 ----
    {
        const int M = 32768;
        mgemm<AM_PLAIN, EP_NONE><<<dim3(768 / 128, M / 128), 256, 0, stream>>>(
            M, 768, 1024, xc_cur, 1024, nullptr, Wib, b_ih, GI, 768, nullptr, nullptr);
        mgemm<AM_PLAIN, EP_NONE><<<dim3(768 / 128, (M / 2) / 128), 256, 0, stream>>>(
            M / 2, 768, 256, hc_prev, 256, nullptr, Whh, b_hh, GH, 768, nullptr, nullptr);
        gates_kernel<<<M, 256, 0, stream>>>(M, GI, (const float*)GH, b_hh, hc_prev, hc_new, 0);
        hb_kernel<<<M / 4, 256, 0, stream>>>(M, xc_cur, hc_new, W_hb, b_hb,
                                             d_prev, out + 1024, 1025, 0);
        copyout_kernel<<<(size_t)(M / 256) * 1024, 256, 0, stream>>>(XCF, out);
    }
}

// Round 3
// 1720.145 us; speedup vs baseline: 4.0666x; 1.0722x over previous
//
#include <hip/hip_runtime.h>
#include <hip/hip_bf16.h>
#include <cstdint>
#include <cstddef>

// ---------------------------------------------------------------------------
// Parser tree expansion — round 3: XCD-local block swizzle, fused epilogues.
// B=64, S=32, H=1024, R=256, DEPTH=9. Output [64, 512, 1025] fp32.
// Child rows of parent m are 2m, 2m+1 (parent = row>>1): repeat == index map.
// ---------------------------------------------------------------------------

#define SELU_L 1.0507009873554805f
#define SELU_A 1.6732632423543772f

__device__ __forceinline__ float selu_f(float x) {
    return x > 0.f ? SELU_L * x : (SELU_L * SELU_A) * (__expf(x) - 1.f);
}
__device__ __forceinline__ float sigmoid_f(float x) {
    return 1.f / (1.f + __expf(-x));
}

typedef __attribute__((ext_vector_type(8))) short s16x8;
typedef __attribute__((ext_vector_type(4))) float f32x4;

__device__ __forceinline__ void gld16(const void* g, void* l) {
    __builtin_amdgcn_global_load_lds(
        (const __attribute__((address_space(1))) uint32_t*)g,
        (__attribute__((address_space(3))) uint32_t*)l, 16, 0, 0);
}

enum { AM_PLAIN = 0, AM_CONCAT = 2 };
enum { EP_NONE = 0, EP_SELU32 = 1, EP_BRANCH = 2, EP_RESID = 3 };

// C = epi(A @ W^T + bias). A: [M,K] bf16 (CONCAT: k<1024 from A, k>=1024 from
// A2 ld 256). W: [N,K] bf16. 128x128 tile, BK=32, global_load_lds width=16,
// chunk-XOR LDS swizzle. XCD-local row-band swizzle when nrow%8==0.
template <int AMODE, int EPI>
__global__ __launch_bounds__(256) void mgemm(
    int M, int N, int K,
    const __hip_bfloat16* __restrict__ A, int lda,
    const __hip_bfloat16* __restrict__ A2,
    const __hip_bfloat16* __restrict__ W,
    const float* __restrict__ bias,
    void* __restrict__ Cv, int ldc,
    const __hip_bfloat16* __restrict__ P,
    float* __restrict__ C32, int ldc32)
{
    __shared__ short As[4096];   // 128 rows x 32 k, chunk-swizzled
    __shared__ short Bs[4096];

    const int tid  = threadIdx.x;
    const int wave = tid >> 6;
    const int lane = tid & 63;

    // ---- XCD-locality swizzle: 8 contiguous row bands, columns fastest ----
    int bxi = blockIdx.x, byi = blockIdx.y;
    {
        const int ncol = gridDim.x, nrow = gridDim.y;
        if ((nrow & 7) == 0) {
            const int lin = byi * ncol + bxi;
            const int xcd = lin & 7;
            const int t = lin >> 3;
            const int rows_per = nrow >> 3;
            bxi = t % ncol;
            byi = xcd * rows_per + t / ncol;
        }
    }
    const int bm = byi * 128;
    const int bn = bxi * 128;

    // ---- staging: slot s holds row s>>2, phys chunk s&3 (XOR row>>1) ----
    const int s0 = wave * 128 + lane;
    const int s1 = s0 + 64;
    const int r0 = s0 >> 2, j0 = ((s0 & 3) - (r0 >> 1)) & 3;
    const int r1 = s1 >> 2, j1 = ((s1 & 3) - (r1 >> 1)) & 3;
    const int ga0 = min(bm + r0, M - 1);
    const int ga1 = min(bm + r1, M - 1);

    const short* gA0; const short* gA1;
    const short* gA0b = nullptr; const short* gA1b = nullptr;
    if (AMODE == AM_CONCAT) {
        gA0  = (const short*)A  + (size_t)ga0 * 1024 + j0 * 8;
        gA1  = (const short*)A  + (size_t)ga1 * 1024 + j1 * 8;
        gA0b = (const short*)A2 + (size_t)ga0 * 256  + j0 * 8;
        gA1b = (const short*)A2 + (size_t)ga1 * 256  + j1 * 8;
    } else {
        gA0 = (const short*)A + (size_t)ga0 * lda + j0 * 8;
        gA1 = (const short*)A + (size_t)ga1 * lda + j1 * 8;
    }
    const short* gB0 = (const short*)W + (size_t)(bn + r0) * K + j0 * 8;
    const short* gB1 = (const short*)W + (size_t)(bn + r1) * K + j1 * 8;

    short* dA0 = &As[wave * 1024];
    short* dA1 = &As[wave * 1024 + 512];
    short* dB0 = &Bs[wave * 1024];
    short* dB1 = &Bs[wave * 1024 + 512];

    // ---- fragment read offsets (k-invariant) ----
    const int wm = (wave >> 1) * 64, wn = (wave & 1) * 64;
    const int l16 = lane & 15, q4 = lane >> 4;
    int aoff[4], boff[4];
#pragma unroll
    for (int i = 0; i < 4; ++i) {
        int ra = wm + i * 16 + l16;
        aoff[i] = ra * 32 + (((q4 + (ra >> 1)) & 3) << 3);
        int rb = wn + i * 16 + l16;
        boff[i] = rb * 32 + (((q4 + (rb >> 1)) & 3) << 3);
    }

    f32x4 acc[4][4] = {};

    for (int k0 = 0; k0 < K; k0 += 32) {
        if (AMODE == AM_CONCAT) {
            const short* a0 = (k0 < 1024) ? gA0 + k0 : gA0b + (k0 - 1024);
            const short* a1 = (k0 < 1024) ? gA1 + k0 : gA1b + (k0 - 1024);
            gld16(a0, dA0);
            gld16(a1, dA1);
        } else {
            gld16(gA0 + k0, dA0);
            gld16(gA1 + k0, dA1);
        }
        gld16(gB0 + k0, dB0);
        gld16(gB1 + k0, dB1);
        __syncthreads();

        s16x8 af[4], bf[4];
#pragma unroll
        for (int i = 0; i < 4; ++i) af[i] = *(const s16x8*)&As[aoff[i]];
#pragma unroll
        for (int i = 0; i < 4; ++i) bf[i] = *(const s16x8*)&Bs[boff[i]];
#pragma unroll
        for (int mi = 0; mi < 4; ++mi)
#pragma unroll
            for (int ni = 0; ni < 4; ++ni)
                acc[mi][ni] = __builtin_amdgcn_mfma_f32_16x16x32_bf16(
                    af[mi], bf[ni], acc[mi][ni], 0, 0, 0);
        __syncthreads();
    }

    // ---- epilogue: C/D layout col=lane&15, row=q4*4+reg ----
    const int crow0 = bm + wm + q4 * 4;
    const int ccol0 = bn + wn + l16;
#pragma unroll
    for (int mi = 0; mi < 4; ++mi) {
#pragma unroll
        for (int r = 0; r < 4; ++r) {
            const int row = crow0 + mi * 16 + r;
            if (row >= M) continue;
#pragma unroll
            for (int ni = 0; ni < 4; ++ni) {
                const int col = ccol0 + ni * 16;
                float v = acc[mi][ni][r] + bias[col];
                if (EPI == EP_NONE) {
                    ((float*)Cv)[(size_t)row * ldc + col] = v;
                } else if (EPI == EP_SELU32) {
                    ((float*)Cv)[(size_t)row * ldc + col] = selu_f(v);
                } else if (EPI == EP_BRANCH) {
                    const int c = col >> 10, jj = col & 1023;
                    ((__hip_bfloat16*)Cv)[(size_t)(2 * row + c) * 1024 + jj] =
                        __float2bfloat16(selu_f(v));
                } else { // EP_RESID
                    const float pv = __bfloat162float(P[(size_t)(row >> 1) * 1024 + col]);
                    const float o = pv - selu_f(v);
                    ((__hip_bfloat16*)Cv)[(size_t)row * 1024 + col] = __float2bfloat16(o);
                    if (C32) C32[(size_t)row * ldc32 + col] = o;
                }
            }
        }
    }
}

// ---- elementwise helpers ----
__global__ void cvt_bf16_k(const float* __restrict__ in, __hip_bfloat16* __restrict__ out, int n)
{
    int i = blockIdx.x * 256 + threadIdx.x;
    if (i < n) out[i] = __float2bfloat16(in[i]);
}

__global__ void selu_cvt_k(const float* __restrict__ in, __hip_bfloat16* __restrict__ out, int n)
{
    int i = blockIdx.x * 256 + threadIdx.x;
    if (i < n) out[i] = __float2bfloat16(selu_f(in[i]));
}

// xc[b,h] = mean_s T[(b*32+s)*1024+h]
__global__ void mean_kernel(const float* __restrict__ T, __hip_bfloat16* __restrict__ xc)
{
    const int idx = blockIdx.x * 256 + threadIdx.x; // 64*1024
    const int b = idx >> 10, h = idx & 1023;
    const float* p = T + (size_t)b * 32 * 1024 + h;
    float s = 0.f;
#pragma unroll
    for (int si = 0; si < 32; ++si) s += p[si * 1024];
    xc[idx] = __float2bfloat16(s * (1.f / 32.f));
}

// Fused GRU gates + hb/depth. One block (256 thr) per row m.
// Thread j: hnew[j] from gi[m], gh[m>>1], hold[m>>1]; contributes
// hnew[j]*W_hb[1024+j] plus 4 strided xc terms to the hb dot.
__global__ __launch_bounds__(256) void gateshb_kernel(
    const float* __restrict__ gi,
    const float* __restrict__ gh,
    const float* __restrict__ b_hh,
    const __hip_bfloat16* __restrict__ hold,
    __hip_bfloat16* __restrict__ hnew,
    const __hip_bfloat16* __restrict__ xc,
    const float* __restrict__ W_hb,
    const float* __restrict__ b_hb,
    const float* __restrict__ depth_old,
    float* __restrict__ depth_out, int dstride,
    int first)
{
    const int m = blockIdx.x;
    const int j = threadIdx.x;
    __shared__ float red[4];

    const float* gim = gi + (size_t)m * 768;
    const float ir = gim[j], iz = gim[256 + j], in_ = gim[512 + j];
    float hr, hz, hn, h0;
    if (first) {
        hr = b_hh[j]; hz = b_hh[256 + j]; hn = b_hh[512 + j]; h0 = 0.f;
    } else {
        const float* ghm = gh + (size_t)(m >> 1) * 768;
        hr = ghm[j]; hz = ghm[256 + j]; hn = ghm[512 + j];
        h0 = __bfloat162float(hold[(size_t)(m >> 1) * 256 + j]);
    }
    const float r = sigmoid_f(ir + hr);
    const float z = sigmoid_f(iz + hz);
    const float n = tanhf(in_ + r * hn);
    const float hv = (1.f - z) * n + z * h0;
    hnew[(size_t)m * 256 + j] = __float2bfloat16(hv);

    // hb dot product
    const __hip_bfloat16* xr = xc + (size_t)m * 1024;
    float s = hv * W_hb[1024 + j];
#pragma unroll
    for (int kk = 0; kk < 4; ++kk) {
        const int k = j + kk * 256;
        s += __bfloat162float(xr[k]) * W_hb[k];
    }
#pragma unroll
    for (int off = 32; off; off >>= 1) s += __shfl_down(s, off);
    if ((j & 63) == 0) red[j >> 6] = s;
    __syncthreads();
    if (j == 0) {
        const float tot = red[0] + red[1] + red[2] + red[3];
        const float hb = sigmoid_f(tot + b_hb[0]);
        const float d0 = first ? 0.f : depth_old[m >> 1];
        depth_out[(size_t)m * dstride] = d0 + hb;
    }
}

extern "C" void kernel_launch(void* const* d_in, const int* in_sizes, int n_in,
                              void* d_out, int out_size, void* d_ws, size_t ws_size,
                              hipStream_t stream)
{
    const float* x        = (const float*)d_in[0];   // [64,32,1024]
    const float* W_hidden = (const float*)d_in[1];   // [1024,1024]
    const float* b_hidden = (const float*)d_in[2];
    const float* W_hb     = (const float*)d_in[3];   // [1,1280]
    const float* b_hb     = (const float*)d_in[4];
    const float* W_branch = (const float*)d_in[5];   // [2048,1280]
    const float* b_branch = (const float*)d_in[6];
    const float* W_ih     = (const float*)d_in[7];   // [768,1024]
    const float* W_hh     = (const float*)d_in[8];   // [768,256]
    const float* b_ih     = (const float*)d_in[9];
    const float* b_hh     = (const float*)d_in[10];

    char* ws = (char*)d_ws;
    size_t off = 0;
    auto alloc = [&](size_t bytes) {
        void* p = ws + off;
        off += (bytes + 255) & ~(size_t)255;
        return p;
    };
    __hip_bfloat16* Whb  = (__hip_bfloat16*)alloc(1024 * 1024 * 2);
    __hip_bfloat16* Wbb  = (__hip_bfloat16*)alloc(2048 * 1280 * 2);
    __hip_bfloat16* Wib  = (__hip_bfloat16*)alloc(768 * 1024 * 2);
    __hip_bfloat16* Whh  = (__hip_bfloat16*)alloc(768 * 256 * 2);
    __hip_bfloat16* Xs   = (__hip_bfloat16*)alloc((size_t)2048 * 1024 * 2);
    float*          GI   = (float*)alloc((size_t)32768 * 768 * 4);       // gi; also root T
    __hip_bfloat16* U    = (__hip_bfloat16*)alloc((size_t)32768 * 1024 * 2); // LR / gh (shared)
    __hip_bfloat16* XC0  = (__hip_bfloat16*)alloc((size_t)32768 * 1024 * 2);
    __hip_bfloat16* XC1  = (__hip_bfloat16*)alloc((size_t)32768 * 1024 * 2);
    __hip_bfloat16* HC0  = (__hip_bfloat16*)alloc((size_t)32768 * 256 * 2);
    __hip_bfloat16* HC1  = (__hip_bfloat16*)alloc((size_t)32768 * 256 * 2);
    float*          D0   = (float*)alloc(32768 * 4);
    float*          D1   = (float*)alloc(32768 * 4);
    float*          GH   = (float*)U;  // gh fp32 [M/2,768], time-shared with LR

    float* out = (float*)d_out; // [32768, 1025]

    // ---- weight + input conversions ----
    cvt_bf16_k<<<(1024 * 1024 + 255) / 256, 256, 0, stream>>>(W_hidden, Whb, 1024 * 1024);
    cvt_bf16_k<<<(2048 * 1280 + 255) / 256, 256, 0, stream>>>(W_branch, Wbb, 2048 * 1280);
    cvt_bf16_k<<<(768 * 1024 + 255) / 256, 256, 0, stream>>>(W_ih, Wib, 768 * 1024);
    cvt_bf16_k<<<(768 * 256 + 255) / 256, 256, 0, stream>>>(W_hh, Whh, 768 * 256);
    selu_cvt_k<<<(2048 * 1024 + 255) / 256, 256, 0, stream>>>(x, Xs, 2048 * 1024);

    // ---- root: T = selu(Xs @ Wh^T + b); xc0 = mean_s(T) ----
    mgemm<AM_PLAIN, EP_SELU32><<<dim3(1024 / 128, 2048 / 128), 256, 0, stream>>>(
        2048, 1024, 1024, Xs, 1024, nullptr, Whb, b_hidden, GI, 1024, nullptr, nullptr, 0);
    mean_kernel<<<(64 * 1024) / 256, 256, 0, stream>>>(GI, XC0);

    __hip_bfloat16* xc_cur = XC0; __hip_bfloat16* xc_next = XC1;
    __hip_bfloat16* hc_prev = nullptr; __hip_bfloat16* hc_new = HC0;
    float* d_prev = nullptr; float* d_next = D0;

    for (int d = 0; d < 9; ++d) {
        const int M = 64 << d; // 64 .. 16384
        mgemm<AM_PLAIN, EP_NONE><<<dim3(768 / 128, (M + 127) / 128), 256, 0, stream>>>(
            M, 768, 1024, xc_cur, 1024, nullptr, Wib, b_ih, GI, 768, nullptr, nullptr, 0);
        if (d > 0) {
            mgemm<AM_PLAIN, EP_NONE><<<dim3(768 / 128, (M / 2 + 127) / 128), 256, 0, stream>>>(
                M / 2, 768, 256, hc_prev, 256, nullptr, Whh, b_hh, GH, 768, nullptr, nullptr, 0);
        }
        gateshb_kernel<<<M, 256, 0, stream>>>(
            GI, (const float*)GH, b_hh, hc_prev, hc_new,
            xc_cur, W_hb, b_hb, d_prev, d_next, 1, d == 0 ? 1 : 0);
        // LR = selu([xc,hc] @ Wb^T + b), interleaved children [2M,1024] bf16
        mgemm<AM_CONCAT, EP_BRANCH><<<dim3(2048 / 128, (M + 127) / 128), 256, 0, stream>>>(
            M, 2048, 1280, xc_cur, 1024, hc_new, Wbb, b_branch, U, 1024, nullptr, nullptr, 0);
        // xc_next[r] = xc_cur[r>>1] - selu(LR[r] @ Wh^T + b); fp32 direct to out at last level
        mgemm<AM_PLAIN, EP_RESID><<<dim3(1024 / 128, (2 * M) / 128), 256, 0, stream>>>(
            2 * M, 1024, 1024, U, 1024, nullptr, Whb, b_hidden, xc_next, 1024,
            xc_cur, d == 8 ? out : nullptr, 1025);

        __hip_bfloat16* t = xc_cur; xc_cur = xc_next; xc_next = t;
        hc_prev = hc_new; hc_new = (hc_new == HC0) ? HC1 : HC0;
        d_prev = d_next;  d_next = (d_next == D0) ? D1 : D0;
    }

    // ---- final GRU + leaf depth, M = 32768 ----
    {
        const int M = 32768;
        mgemm<AM_PLAIN, EP_NONE><<<dim3(768 / 128, M / 128), 256, 0, stream>>>(
            M, 768, 1024, xc_cur, 1024, nullptr, Wib, b_ih, GI, 768, nullptr, nullptr, 0);
        mgemm<AM_PLAIN, EP_NONE><<<dim3(768 / 128, (M / 2) / 128), 256, 0, stream>>>(
            M / 2, 768, 256, hc_prev, 256, nullptr, Whh, b_hh, GH, 768, nullptr, nullptr, 0);
        gateshb_kernel<<<M, 256, 0, stream>>>(
            GI, (const float*)GH, b_hh, hc_prev, hc_new,
            xc_cur, W_hb, b_hb, d_prev, out + 1024, 1025, 0);
    }
}

// Round 4
// 1488.607 us; speedup vs baseline: 4.6991x; 1.1555x over previous
//
#include <hip/hip_runtime.h>
#include <hip/hip_bf16.h>
#include <cstdint>
#include <cstddef>

// ---------------------------------------------------------------------------
// Parser tree expansion — round 4: BK=64 K-loop (32 MFMA per barrier),
// gi+gh dual-GEMM launch, fused weight converts.
// B=64, S=32, H=1024, R=256, DEPTH=9. Output [64, 512, 1025] fp32.
// Child rows of parent m are 2m, 2m+1 (parent = row>>1): repeat == index map.
// ---------------------------------------------------------------------------

#define SELU_L 1.0507009873554805f
#define SELU_A 1.6732632423543772f

__device__ __forceinline__ float selu_f(float x) {
    return x > 0.f ? SELU_L * x : (SELU_L * SELU_A) * (__expf(x) - 1.f);
}
__device__ __forceinline__ float sigmoid_f(float x) {
    return 1.f / (1.f + __expf(-x));
}

typedef __attribute__((ext_vector_type(8))) short s16x8;
typedef __attribute__((ext_vector_type(4))) float f32x4;

__device__ __forceinline__ void gld16(const void* g, void* l) {
    __builtin_amdgcn_global_load_lds(
        (const __attribute__((address_space(1))) uint32_t*)g,
        (__attribute__((address_space(3))) uint32_t*)l, 16, 0, 0);
}

enum { AM_PLAIN = 0, AM_CONCAT = 2 };
enum { EP_NONE = 0, EP_SELU32 = 1, EP_BRANCH = 2, EP_RESID = 3 };

// Shared GEMM body: 128x128 tile, BK=64, 4 waves x (4x4 16x16x32 bf16 frags).
// LDS: 128 rows x 64 k per tensor, 8-chunk XOR swizzle (pc = (j + row>>1)&7).
// Two 32-k sub-steps per barrier pair -> 32 MFMAs between barriers.
template <int AMODE, int EPI>
__device__ __forceinline__ void gemm_body(
    int bm, int bn, int M, int K,
    const __hip_bfloat16* __restrict__ A, int lda,
    const __hip_bfloat16* __restrict__ A2,
    const __hip_bfloat16* __restrict__ W,
    const float* __restrict__ bias,
    void* __restrict__ Cv, int ldc,
    const __hip_bfloat16* __restrict__ P,
    float* __restrict__ C32, int ldc32,
    short* As, short* Bs)
{
    const int tid  = threadIdx.x;
    const int wave = tid >> 6;
    const int lane = tid & 63;

    // ---- staging: 4 rounds per tensor; slot s = r*256 + wave*64 + lane ----
    const short* gA[4]; const short* gA2p[4]; const short* gB[4];
    short* dA[4]; short* dB[4];
#pragma unroll
    for (int r = 0; r < 4; ++r) {
        const int s   = r * 256 + wave * 64 + lane;
        const int row = s >> 3;
        const int pc  = s & 7;
        const int j   = (pc - (row >> 1)) & 7;   // logical 8-k chunk
        const int ga  = min(bm + row, M - 1);
        if (AMODE == AM_CONCAT) {
            gA[r]   = (const short*)A  + (size_t)ga * 1024 + j * 8;
            gA2p[r] = (const short*)A2 + (size_t)ga * 256  + j * 8;
        } else {
            gA[r]   = (const short*)A + (size_t)ga * lda + j * 8;
            gA2p[r] = nullptr;
        }
        gB[r] = (const short*)W + (size_t)(bn + row) * K + j * 8;
        dA[r] = &As[(size_t)(r * 256 + wave * 64) * 8];
        dB[r] = &Bs[(size_t)(r * 256 + wave * 64) * 8];
    }

    // ---- fragment read offsets (k-invariant; second 32-k half = off^32) ----
    const int wm = (wave >> 1) * 64, wn = (wave & 1) * 64;
    const int l16 = lane & 15, q4 = lane >> 4;
    int aoff[4], boff[4];
#pragma unroll
    for (int i = 0; i < 4; ++i) {
        int ra = wm + i * 16 + l16;
        aoff[i] = ra * 64 + (((q4 + (ra >> 1)) & 7) << 3);
        int rb = wn + i * 16 + l16;
        boff[i] = rb * 64 + (((q4 + (rb >> 1)) & 7) << 3);
    }

    f32x4 acc[4][4] = {};

    for (int k0 = 0; k0 < K; k0 += 64) {
#pragma unroll
        for (int r = 0; r < 4; ++r) {
            const short* ap;
            if (AMODE == AM_CONCAT)
                ap = (k0 < 1024) ? gA[r] + k0 : gA2p[r] + (k0 - 1024);
            else
                ap = gA[r] + k0;
            gld16(ap, dA[r]);
            gld16(gB[r] + k0, dB[r]);
        }
        __syncthreads();

#pragma unroll
        for (int h = 0; h < 2; ++h) {
            const int hx = h << 5;  // ^32 flips chunk field (+4 mod 8)
            s16x8 af[4], bf[4];
#pragma unroll
            for (int i = 0; i < 4; ++i) af[i] = *(const s16x8*)&As[aoff[i] ^ hx];
#pragma unroll
            for (int i = 0; i < 4; ++i) bf[i] = *(const s16x8*)&Bs[boff[i] ^ hx];
#pragma unroll
            for (int mi = 0; mi < 4; ++mi)
#pragma unroll
                for (int ni = 0; ni < 4; ++ni)
                    acc[mi][ni] = __builtin_amdgcn_mfma_f32_16x16x32_bf16(
                        af[mi], bf[ni], acc[mi][ni], 0, 0, 0);
        }
        __syncthreads();
    }

    // ---- epilogue: C/D layout col=lane&15, row=q4*4+reg ----
    const int crow0 = bm + wm + q4 * 4;
    const int ccol0 = bn + wn + l16;
#pragma unroll
    for (int mi = 0; mi < 4; ++mi) {
#pragma unroll
        for (int r = 0; r < 4; ++r) {
            const int row = crow0 + mi * 16 + r;
            if (row >= M) continue;
#pragma unroll
            for (int ni = 0; ni < 4; ++ni) {
                const int col = ccol0 + ni * 16;
                float v = acc[mi][ni][r] + bias[col];
                if (EPI == EP_NONE) {
                    ((float*)Cv)[(size_t)row * ldc + col] = v;
                } else if (EPI == EP_SELU32) {
                    ((float*)Cv)[(size_t)row * ldc + col] = selu_f(v);
                } else if (EPI == EP_BRANCH) {
                    const int c = col >> 10, jj = col & 1023;
                    ((__hip_bfloat16*)Cv)[(size_t)(2 * row + c) * 1024 + jj] =
                        __float2bfloat16(selu_f(v));
                } else { // EP_RESID
                    const float pv = __bfloat162float(P[(size_t)(row >> 1) * 1024 + col]);
                    const float o = pv - selu_f(v);
                    ((__hip_bfloat16*)Cv)[(size_t)row * 1024 + col] = __float2bfloat16(o);
                    if (C32) C32[(size_t)row * ldc32 + col] = o;
                }
            }
        }
    }
}

// Single-problem wrapper with XCD-local row-band swizzle.
template <int AMODE, int EPI>
__global__ __launch_bounds__(256) void mgemm(
    int M, int N, int K,
    const __hip_bfloat16* __restrict__ A, int lda,
    const __hip_bfloat16* __restrict__ A2,
    const __hip_bfloat16* __restrict__ W,
    const float* __restrict__ bias,
    void* __restrict__ Cv, int ldc,
    const __hip_bfloat16* __restrict__ P,
    float* __restrict__ C32, int ldc32)
{
    __shared__ short As[8192];
    __shared__ short Bs[8192];
    int bxi = blockIdx.x, byi = blockIdx.y;
    {
        const int ncol = gridDim.x, nrow = gridDim.y;
        if ((nrow & 7) == 0) {
            const int lin = byi * ncol + bxi;
            const int xcd = lin & 7;
            const int t = lin >> 3;
            const int rows_per = nrow >> 3;
            bxi = t % ncol;
            byi = xcd * rows_per + t / ncol;
        }
    }
    gemm_body<AMODE, EPI>(byi * 128, bxi * 128, M, K, A, lda, A2, W, bias,
                          Cv, ldc, P, C32, ldc32, As, Bs);
}

// Dual gi+gh launch: z=0 -> problem 0 (gi), z=1 -> problem 1 (gh, smaller M).
struct GPair {
    int M0, K0; const __hip_bfloat16* A0; int lda0;
    const __hip_bfloat16* W0; const float* b0; float* C0; int ldc0;
    int M1, K1; const __hip_bfloat16* A1; int lda1;
    const __hip_bfloat16* W1; const float* b1; float* C1; int ldc1;
};
__global__ __launch_bounds__(256) void mgemm_pair(GPair g)
{
    __shared__ short As[8192];
    __shared__ short Bs[8192];
    int bxi = blockIdx.x, byi = blockIdx.y;
    if (blockIdx.z == 0) {
        const int ncol = gridDim.x, nrow = gridDim.y;
        if ((nrow & 7) == 0) {
            const int lin = byi * ncol + bxi;
            const int xcd = lin & 7;
            const int t = lin >> 3;
            const int rows_per = nrow >> 3;
            bxi = t % ncol;
            byi = xcd * rows_per + t / ncol;
        }
        gemm_body<AM_PLAIN, EP_NONE>(byi * 128, bxi * 128, g.M0, g.K0,
                                     g.A0, g.lda0, nullptr, g.W0, g.b0,
                                     g.C0, g.ldc0, nullptr, nullptr, 0, As, Bs);
    } else {
        if (byi * 128 >= g.M1) return;
        gemm_body<AM_PLAIN, EP_NONE>(byi * 128, bxi * 128, g.M1, g.K1,
                                     g.A1, g.lda1, nullptr, g.W1, g.b1,
                                     g.C1, g.ldc1, nullptr, nullptr, 0, As, Bs);
    }
}

// ---- elementwise helpers ----
__global__ void cvt4_k(const float* __restrict__ s0, __hip_bfloat16* __restrict__ d0, int n0,
                       const float* __restrict__ s1, __hip_bfloat16* __restrict__ d1, int n1,
                       const float* __restrict__ s2, __hip_bfloat16* __restrict__ d2, int n2,
                       const float* __restrict__ s3, __hip_bfloat16* __restrict__ d3, int n3)
{
    int i = blockIdx.x * 256 + threadIdx.x;
    if (i < n0) { d0[i] = __float2bfloat16(s0[i]); return; }
    i -= n0;
    if (i < n1) { d1[i] = __float2bfloat16(s1[i]); return; }
    i -= n1;
    if (i < n2) { d2[i] = __float2bfloat16(s2[i]); return; }
    i -= n2;
    if (i < n3) { d3[i] = __float2bfloat16(s3[i]); }
}

__global__ void selu_cvt_k(const float* __restrict__ in, __hip_bfloat16* __restrict__ out, int n)
{
    int i = blockIdx.x * 256 + threadIdx.x;
    if (i < n) out[i] = __float2bfloat16(selu_f(in[i]));
}

// xc[b,h] = mean_s T[(b*32+s)*1024+h]
__global__ void mean_kernel(const float* __restrict__ T, __hip_bfloat16* __restrict__ xc)
{
    const int idx = blockIdx.x * 256 + threadIdx.x; // 64*1024
    const int b = idx >> 10, h = idx & 1023;
    const float* p = T + (size_t)b * 32 * 1024 + h;
    float s = 0.f;
#pragma unroll
    for (int si = 0; si < 32; ++si) s += p[si * 1024];
    xc[idx] = __float2bfloat16(s * (1.f / 32.f));
}

// Fused GRU gates + hb/depth. One block (256 thr) per row m.
__global__ __launch_bounds__(256) void gateshb_kernel(
    const float* __restrict__ gi,
    const float* __restrict__ gh,
    const float* __restrict__ b_hh,
    const __hip_bfloat16* __restrict__ hold,
    __hip_bfloat16* __restrict__ hnew,
    const __hip_bfloat16* __restrict__ xc,
    const float* __restrict__ W_hb,
    const float* __restrict__ b_hb,
    const float* __restrict__ depth_old,
    float* __restrict__ depth_out, int dstride,
    int first)
{
    const int m = blockIdx.x;
    const int j = threadIdx.x;
    __shared__ float red[4];

    const float* gim = gi + (size_t)m * 768;
    const float ir = gim[j], iz = gim[256 + j], in_ = gim[512 + j];
    float hr, hz, hn, h0;
    if (first) {
        hr = b_hh[j]; hz = b_hh[256 + j]; hn = b_hh[512 + j]; h0 = 0.f;
    } else {
        const float* ghm = gh + (size_t)(m >> 1) * 768;
        hr = ghm[j]; hz = ghm[256 + j]; hn = ghm[512 + j];
        h0 = __bfloat162float(hold[(size_t)(m >> 1) * 256 + j]);
    }
    const float r = sigmoid_f(ir + hr);
    const float z = sigmoid_f(iz + hz);
    const float n = tanhf(in_ + r * hn);
    const float hv = (1.f - z) * n + z * h0;
    hnew[(size_t)m * 256 + j] = __float2bfloat16(hv);

    const __hip_bfloat16* xr = xc + (size_t)m * 1024;
    float s = hv * W_hb[1024 + j];
#pragma unroll
    for (int kk = 0; kk < 4; ++kk) {
        const int k = j + kk * 256;
        s += __bfloat162float(xr[k]) * W_hb[k];
    }
#pragma unroll
    for (int off = 32; off; off >>= 1) s += __shfl_down(s, off);
    if ((j & 63) == 0) red[j >> 6] = s;
    __syncthreads();
    if (j == 0) {
        const float tot = red[0] + red[1] + red[2] + red[3];
        const float hb = sigmoid_f(tot + b_hb[0]);
        const float d0 = first ? 0.f : depth_old[m >> 1];
        depth_out[(size_t)m * dstride] = d0 + hb;
    }
}

extern "C" void kernel_launch(void* const* d_in, const int* in_sizes, int n_in,
                              void* d_out, int out_size, void* d_ws, size_t ws_size,
                              hipStream_t stream)
{
    const float* x        = (const float*)d_in[0];   // [64,32,1024]
    const float* W_hidden = (const float*)d_in[1];   // [1024,1024]
    const float* b_hidden = (const float*)d_in[2];
    const float* W_hb     = (const float*)d_in[3];   // [1,1280]
    const float* b_hb     = (const float*)d_in[4];
    const float* W_branch = (const float*)d_in[5];   // [2048,1280]
    const float* b_branch = (const float*)d_in[6];
    const float* W_ih     = (const float*)d_in[7];   // [768,1024]
    const float* W_hh     = (const float*)d_in[8];   // [768,256]
    const float* b_ih     = (const float*)d_in[9];
    const float* b_hh     = (const float*)d_in[10];

    char* ws = (char*)d_ws;
    size_t off = 0;
    auto alloc = [&](size_t bytes) {
        void* p = ws + off;
        off += (bytes + 255) & ~(size_t)255;
        return p;
    };
    __hip_bfloat16* Whb  = (__hip_bfloat16*)alloc(1024 * 1024 * 2);
    __hip_bfloat16* Wbb  = (__hip_bfloat16*)alloc(2048 * 1280 * 2);
    __hip_bfloat16* Wib  = (__hip_bfloat16*)alloc(768 * 1024 * 2);
    __hip_bfloat16* Whh  = (__hip_bfloat16*)alloc(768 * 256 * 2);
    __hip_bfloat16* Xs   = (__hip_bfloat16*)alloc((size_t)2048 * 1024 * 2);
    float*          GI   = (float*)alloc((size_t)32768 * 768 * 4);       // gi; also root T
    __hip_bfloat16* U    = (__hip_bfloat16*)alloc((size_t)32768 * 1024 * 2); // LR / gh (shared)
    __hip_bfloat16* XC0  = (__hip_bfloat16*)alloc((size_t)32768 * 1024 * 2);
    __hip_bfloat16* XC1  = (__hip_bfloat16*)alloc((size_t)32768 * 1024 * 2);
    __hip_bfloat16* HC0  = (__hip_bfloat16*)alloc((size_t)32768 * 256 * 2);
    __hip_bfloat16* HC1  = (__hip_bfloat16*)alloc((size_t)32768 * 256 * 2);
    float*          D0   = (float*)alloc(32768 * 4);
    float*          D1   = (float*)alloc(32768 * 4);
    float*          GH   = (float*)U;  // gh fp32 [M/2,768], time-shared with LR

    float* out = (float*)d_out; // [32768, 1025]

    // ---- weight + input conversions (2 launches) ----
    {
        const int n0 = 1024 * 1024, n1 = 2048 * 1280, n2 = 768 * 1024, n3 = 768 * 256;
        cvt4_k<<<(n0 + n1 + n2 + n3 + 255) / 256, 256, 0, stream>>>(
            W_hidden, Whb, n0, W_branch, Wbb, n1, W_ih, Wib, n2, W_hh, Whh, n3);
    }
    selu_cvt_k<<<(2048 * 1024 + 255) / 256, 256, 0, stream>>>(x, Xs, 2048 * 1024);

    // ---- root: T = selu(Xs @ Wh^T + b); xc0 = mean_s(T) ----
    mgemm<AM_PLAIN, EP_SELU32><<<dim3(1024 / 128, 2048 / 128), 256, 0, stream>>>(
        2048, 1024, 1024, Xs, 1024, nullptr, Whb, b_hidden, GI, 1024, nullptr, nullptr, 0);
    mean_kernel<<<(64 * 1024) / 256, 256, 0, stream>>>(GI, XC0);

    __hip_bfloat16* xc_cur = XC0; __hip_bfloat16* xc_next = XC1;
    __hip_bfloat16* hc_prev = nullptr; __hip_bfloat16* hc_new = HC0;
    float* d_prev = nullptr; float* d_next = D0;

    for (int d = 0; d < 9; ++d) {
        const int M = 64 << d; // 64 .. 16384
        // gi (+ gh for d>0) in one launch
        GPair g;
        g.M0 = M;     g.K0 = 1024; g.A0 = xc_cur;  g.lda0 = 1024;
        g.W0 = Wib;   g.b0 = b_ih; g.C0 = GI;      g.ldc0 = 768;
        g.M1 = M / 2; g.K1 = 256;  g.A1 = hc_prev; g.lda1 = 256;
        g.W1 = Whh;   g.b1 = b_hh; g.C1 = GH;      g.ldc1 = 768;
        mgemm_pair<<<dim3(768 / 128, (M + 127) / 128, d > 0 ? 2 : 1), 256, 0, stream>>>(g);

        gateshb_kernel<<<M, 256, 0, stream>>>(
            GI, (const float*)GH, b_hh, hc_prev, hc_new,
            xc_cur, W_hb, b_hb, d_prev, d_next, 1, d == 0 ? 1 : 0);
        // LR = selu([xc,hc] @ Wb^T + b), interleaved children [2M,1024] bf16
        mgemm<AM_CONCAT, EP_BRANCH><<<dim3(2048 / 128, (M + 127) / 128), 256, 0, stream>>>(
            M, 2048, 1280, xc_cur, 1024, hc_new, Wbb, b_branch, U, 1024, nullptr, nullptr, 0);
        // xc_next[r] = xc_cur[r>>1] - selu(LR[r] @ Wh^T + b); fp32 direct to out at last level
        mgemm<AM_PLAIN, EP_RESID><<<dim3(1024 / 128, (2 * M) / 128), 256, 0, stream>>>(
            2 * M, 1024, 1024, U, 1024, nullptr, Whb, b_hidden, xc_next, 1024,
            xc_cur, d == 8 ? out : nullptr, 1025);

        __hip_bfloat16* t = xc_cur; xc_cur = xc_next; xc_next = t;
        hc_prev = hc_new; hc_new = (hc_new == HC0) ? HC1 : HC0;
        d_prev = d_next;  d_next = (d_next == D0) ? D1 : D0;
    }

    // ---- final GRU + leaf depth, M = 32768 ----
    {
        const int M = 32768;
        GPair g;
        g.M0 = M;     g.K0 = 1024; g.A0 = xc_cur;  g.lda0 = 1024;
        g.W0 = Wib;   g.b0 = b_ih; g.C0 = GI;      g.ldc0 = 768;
        g.M1 = M / 2; g.K1 = 256;  g.A1 = hc_prev; g.lda1 = 256;
        g.W1 = Whh;   g.b1 = b_hh; g.C1 = GH;      g.ldc1 = 768;
        mgemm_pair<<<dim3(768 / 128, M / 128, 2), 256, 0, stream>>>(g);
        gateshb_kernel<<<M, 256, 0, stream>>>(
            GI, (const float*)GH, b_hh, hc_prev, hc_new,
            xc_cur, W_hb, b_hb, d_prev, out + 1024, 1025, 0);
    }
}